// Round 9
// baseline (1193.571 us; speedup 1.0000x reference)
//
#include <hip/hip_runtime.h>
#include <hip/hip_bf16.h>

#define NU 200000
#define NM 80000
#define NT 280000   // NU + NM
#define HD 64
#define FM 20

#define BSHIFT 10
#define NBUCK ((NT + 1023) >> 10)   // 274 buckets of 1024 nodes
#define CHUNK 8192

typedef __attribute__((ext_vector_type(8))) short short8;
typedef __attribute__((ext_vector_type(4))) float floatx4;

__device__ __forceinline__ float bfu2f(unsigned short u) {
    union { unsigned int u; float f; } c; c.u = ((unsigned int)u) << 16; return c.f;
}

__device__ __forceinline__ unsigned short f2bf_raw(float f) {
    union { float f; unsigned int u; } c; c.f = f;
    unsigned int u = c.u + 0x7FFFu + ((c.u >> 16) & 1u);   // round-nearest-even
    return (unsigned short)(u >> 16);
}

__device__ __forceinline__ float ldf(const void* p, long i, int isbf) {
    return isbf ? bfu2f(((const unsigned short*)p)[i]) : ((const float*)p)[i];
}
__device__ __forceinline__ int ldidx(const int* p, long j, int is64) {
    return is64 ? p[2 * j] : p[j];
}

// ---------------- runtime dtype probe -> flags[0]=isbf16, flags[1]=isint64
__global__ void probe_kernel(const void* user_emb, const int* ei, int* flags) {
    int t = threadIdx.x;
    int bad = 0;
    for (int i = t; i < 128; i += 64) {
        unsigned short h = ((const unsigned short*)user_emb)[i];
        unsigned int e = (h >> 7) & 0xFF;
        if (e >= 135) bad = 1;               // |x| >= 256, or Inf/NaN -> not real bf16
    }
    unsigned long long mf = __ballot(bad != 0);
    int odd_nonzero = 0;
    if (t < 16 && ei[2 * t + 1] != 0) odd_nonzero = 1;
    unsigned long long mi = __ballot(odd_nonzero != 0);
    if (t == 0) {
        flags[0] = (mf == 0) ? 1 : 0;
        flags[1] = (mi == 0) ? 1 : 0;
    }
}

// ---------------- prep A: user rows, vectorized copy/convert (8 elems/thread)
__global__ __launch_bounds__(256) void prep_user(
    const void* __restrict__ user_emb,
    unsigned short* __restrict__ xb,
    const int* __restrict__ flags)
{
    long t = (long)blockIdx.x * 256 + threadIdx.x;        // t < NU*HD/8 = 1.6M exactly
    int isbf = flags[0];
    if (isbf) {
        ((short8*)xb)[t] = ((const short8*)user_emb)[t];
    } else {
        floatx4 a = ((const floatx4*)user_emb)[2 * t];
        floatx4 b = ((const floatx4*)user_emb)[2 * t + 1];
        short8 r;
        r[0] = (short)f2bf_raw(a[0]); r[1] = (short)f2bf_raw(a[1]);
        r[2] = (short)f2bf_raw(a[2]); r[3] = (short)f2bf_raw(a[3]);
        r[4] = (short)f2bf_raw(b[0]); r[5] = (short)f2bf_raw(b[1]);
        r[6] = (short)f2bf_raw(b[2]); r[7] = (short)f2bf_raw(b[3]);
        ((short8*)xb)[t] = r;
    }
}

// ---------------- prep B: movie rows. lin_W transposed in LDS; movie_x row via shfl.
__global__ __launch_bounds__(256) void prep_movie(
    const void* __restrict__ movie_x,
    const void* __restrict__ movie_emb,
    const void* __restrict__ lin_W,
    const void* __restrict__ lin_b,
    unsigned short* __restrict__ xb,
    const int* __restrict__ flags)
{
    __shared__ float lWT[FM * HD];   // [k][h] layout -> conflict-free reads
    __shared__ float lb[HD];
    int tid = threadIdx.x;
    int isbf = flags[0];
    for (int i = tid; i < FM * HD; i += 256) {
        int k = i >> 6, h = i & 63;
        lWT[i] = ldf(lin_W, (long)h * FM + k, isbf);
    }
    if (tid < HD) lb[tid] = ldf(lin_b, tid, isbf);
    __syncthreads();

    int m = (blockIdx.x * 256 + tid) >> 6;    // movie id, one wave per movie
    int lane = tid & 63;
    if (m >= NM) return;
    float mxv = (lane < FM) ? ldf(movie_x, (long)m * FM + lane, isbf) : 0.f;
    float acc = lb[lane] + ldf(movie_emb, (long)m * HD + lane, isbf);
    #pragma unroll
    for (int k = 0; k < FM; ++k)
        acc += __shfl(mxv, k) * lWT[k * HD + lane];
    xb[(long)(NU + m) * HD + lane] = f2bf_raw(acc);
}

// ---------------- prep W: convert all layer weights/biases to bf16 scratch
// wbuf layout: [0)W1l [4096)W1r [8192)W2l [12288)W2r [16384)b1 [16448)b2  (16512 elems)
__global__ __launch_bounds__(256) void prep_w(
    const void* __restrict__ W1l, const void* __restrict__ W1r,
    const void* __restrict__ W2l, const void* __restrict__ W2r,
    const void* __restrict__ b1,  const void* __restrict__ b2,
    unsigned short* __restrict__ wbuf,
    const int* __restrict__ flags)
{
    int i = blockIdx.x * 256 + threadIdx.x;
    if (i >= 16512) return;
    int isbf = flags[0];
    float v;
    if      (i < 4096)  v = ldf(W1l, i, isbf);
    else if (i < 8192)  v = ldf(W1r, i - 4096, isbf);
    else if (i < 12288) v = ldf(W2l, i - 8192, isbf);
    else if (i < 16384) v = ldf(W2r, i - 12288, isbf);
    else if (i < 16448) v = ldf(b1, i - 16384, isbf);
    else                v = ldf(b2, i - 16448, isbf);
    wbuf[i] = f2bf_raw(v);
}

// ---------------- CSR build ----------------
__global__ __launch_bounds__(256) void hist_kernel(
    const int* __restrict__ ei, int E, int* __restrict__ cnt, const int* __restrict__ flags)
{
    long e = (long)blockIdx.x * 256 + threadIdx.x;
    if (e >= E) return;
    int d = ldidx(ei, (long)E + e, flags[1]);
    atomicAdd(&cnt[d], 1);
}

__global__ __launch_bounds__(256) void scan1_kernel(const int* __restrict__ cnt, int* __restrict__ bsum)
{
    __shared__ int s[256];
    int t = threadIdx.x;
    long i = (long)blockIdx.x * 256 + t;
    s[t] = (i < NT) ? cnt[i] : 0;
    __syncthreads();
    for (int off = 128; off > 0; off >>= 1) {
        if (t < off) s[t] += s[t + off];
        __syncthreads();
    }
    if (t == 0) bsum[blockIdx.x] = s[0];
}

__global__ __launch_bounds__(256) void scan2_kernel(int* __restrict__ bsum, int NB)
{
    __shared__ int chunk[256];
    int t = threadIdx.x;
    int per = (NB + 255) / 256;
    int begin = t * per;
    int end = begin + per; if (end > NB) end = NB; if (begin > NB) begin = NB;
    int sum = 0;
    for (int i = begin; i < end; ++i) sum += bsum[i];
    chunk[t] = sum;
    __syncthreads();
    for (int off = 1; off < 256; off <<= 1) {
        int v = chunk[t];
        if (t >= off) v += chunk[t - off];
        __syncthreads();
        chunk[t] = v;
        __syncthreads();
    }
    int run = (t == 0) ? 0 : chunk[t - 1];
    for (int i = begin; i < end; ++i) {
        int v = bsum[i];
        bsum[i] = run;
        run += v;
    }
}

__global__ __launch_bounds__(256) void scan3_kernel(
    const int* __restrict__ cnt, const int* __restrict__ bsum,
    int* __restrict__ rowptr)
{
    __shared__ int s[256];
    int t = threadIdx.x;
    long i = (long)blockIdx.x * 256 + t;
    int v = (i < NT) ? cnt[i] : 0;
    s[t] = v;
    __syncthreads();
    for (int off = 1; off < 256; off <<= 1) {
        int u = s[t];
        if (t >= off) u += s[t - off];
        __syncthreads();
        s[t] = u;
        __syncthreads();
    }
    if (i < NT) rowptr[i] = bsum[blockIdx.x] + s[t] - v;   // exclusive
}

// ---------------- bucket pass: group edges by dst>>10 into packed buffer (coalesced runs)
// packed entry: (src << 10) | (dst & 1023); bucket b's region = [rowptr[b<<10], ...)
__global__ __launch_bounds__(256) void bucket_kernel(
    const int* __restrict__ ei, int E,
    const int* __restrict__ rowptr,
    int* __restrict__ bfill,           // NBUCK cursors, pre-zeroed
    int* __restrict__ packed,
    const int* __restrict__ flags)
{
    __shared__ int hist[NBUCK];
    __shared__ int loff[NBUCK + 1];
    __shared__ int cur[NBUCK];
    __shared__ int wbase[NBUCK];
    __shared__ int stage[CHUNK];

    int tid = threadIdx.x;
    int is64 = flags[1];
    long e0 = (long)blockIdx.x * CHUNK;
    long rem = (long)E - e0;
    int n = (rem < CHUNK) ? (int)rem : CHUNK;
    if (n <= 0) return;

    for (int i = tid; i < NBUCK; i += 256) { hist[i] = 0; cur[i] = 0; }
    __syncthreads();
    for (int j = tid; j < n; j += 256) {
        int d = ldidx(ei, (long)E + e0 + j, is64);
        atomicAdd(&hist[d >> BSHIFT], 1);
    }
    __syncthreads();
    if (tid == 0) {                      // serial excl-scan over 274 entries (cheap)
        int run = 0;
        for (int b = 0; b < NBUCK; ++b) { loff[b] = run; run += hist[b]; }
        loff[NBUCK] = run;
    }
    __syncthreads();
    for (int b = tid; b < NBUCK; b += 256) {
        int h = hist[b];
        int g = (h > 0) ? atomicAdd(&bfill[b], h) : 0;
        wbase[b] = rowptr[b << BSHIFT] + g - loff[b];
    }
    __syncthreads();
    for (int j = tid; j < n; j += 256) {
        int s = ldidx(ei, e0 + j, is64);
        int d = ldidx(ei, (long)E + e0 + j, is64);
        int b = d >> BSHIFT;
        int lpos = loff[b] + atomicAdd(&cur[b], 1);
        stage[lpos] = (s << BSHIFT) | (d & ((1 << BSHIFT) - 1));
    }
    __syncthreads();
    for (int j = tid; j < n; j += 256) {
        int lo = 0, hi = NBUCK;          // find b: loff[b] <= j < loff[b+1]
        while (hi - lo > 1) { int mid = (lo + hi) >> 1; if (loff[mid] <= j) lo = mid; else hi = mid; }
        packed[wbase[lo] + j] = stage[j];
    }
}

// ---------------- fine fill: one block per bucket; writes srclist + local-dst byte
__global__ __launch_bounds__(256) void finefill_kernel(
    const int* __restrict__ rowptr,
    const int* __restrict__ packed,
    int* __restrict__ srclist,
    unsigned char* __restrict__ dloc,
    int E)
{
    __shared__ int lfill[1 << BSHIFT];
    int b = blockIdx.x;
    int tid = threadIdx.x;
    int nbase = b << BSHIFT;
    int nend = nbase + (1 << BSHIFT); if (nend > NT) nend = NT;
    int nloc = nend - nbase;
    for (int i = tid; i < nloc; i += 256) lfill[i] = rowptr[nbase + i];
    __syncthreads();
    int beg = rowptr[nbase];
    int end = (nend < NT) ? rowptr[nend] : E;
    for (int j = beg + tid; j < end; j += 256) {
        int p = packed[j];
        int dl = p & ((1 << BSHIFT) - 1);
        int pos = atomicAdd(&lfill[dl], 1);
        srclist[pos] = p >> BSHIFT;
        dloc[pos] = (unsigned char)(dl & 63);   // tiles 64-aligned => dst&63 == dl&63
    }
}

// ---------------- fused SAGE layer: edge-parallel LDS-atomic mean + MFMA combine
// block = 64-node tile. out must NOT alias xin (other blocks' rows are gathered).
template <bool RELU>
__global__ __launch_bounds__(256) void sage_fused(
    const unsigned short* __restrict__ xin,
    const int* __restrict__ rowptr,
    const int* __restrict__ cnt,
    const int* __restrict__ srclist,
    const unsigned char* __restrict__ dloc,
    const unsigned short* __restrict__ Wl,     // bf16 [64][64]
    const unsigned short* __restrict__ bias,   // bf16 [64]
    const unsigned short* __restrict__ Wr,     // bf16 [64][64]
    unsigned short* __restrict__ out,
    int E)
{
    __shared__ float acc[HD * HD];              // 16 KB f32 accumulator tile
    __shared__ unsigned short lmean[HD * HD];   // 8 KB bf16 mean tile
    __shared__ float lb[HD];
    __shared__ float lrd[HD];

    int tid = threadIdx.x;
    int tile = blockIdx.x;
    int t0 = tile * 64;

    for (int i = tid; i < HD * HD; i += 256) acc[i] = 0.f;
    if (tid < HD) {
        lb[tid] = bfu2f(bias[tid]);
        lrd[tid] = 1.0f / fmaxf((float)cnt[t0 + tid], 1.0f);
    }
    __syncthreads();

    // edge-parallel accumulate: 8 lanes per edge (16B chunks), 32 edges per block-iter
    int beg = rowptr[t0];
    int end = (t0 + 64 < NT) ? rowptr[t0 + 64] : E;
    int slot = tid >> 3;        // 0..31
    int seg  = tid & 7;         // 0..7
    for (int e = beg + slot; e < end; e += 32) {
        int s = srclist[e];
        int d6 = dloc[e];
        short8 r = *(const short8*)&xin[(long)s * HD + seg * 8];
        #pragma unroll
        for (int k = 0; k < 8; ++k)
            atomicAdd(&acc[d6 * HD + seg * 8 + k], bfu2f((unsigned short)r[k]));
    }
    __syncthreads();

    // mean -> bf16
    for (int i = tid; i < HD * HD; i += 256) {
        int node = i >> 6;
        lmean[i] = f2bf_raw(acc[i] * lrd[node]);
    }
    __syncthreads();

    // MFMA combine: out = act(mean @ Wl.T + b + xin @ Wr.T)
    int w = tid >> 6;
    int lane = tid & 63;
    int mrow = lane & 15;
    int quad = lane >> 4;

    short8 am0 = *(const short8*)&lmean[(w * 16 + mrow) * HD + quad * 8];
    short8 am1 = *(const short8*)&lmean[(w * 16 + mrow) * HD + 32 + quad * 8];
    const unsigned short* xrow = xin + ((long)(t0 + w * 16 + mrow)) * HD;
    short8 ax0 = *(const short8*)&xrow[quad * 8];
    short8 ax1 = *(const short8*)&xrow[32 + quad * 8];

    floatx4 accv[4];
    #pragma unroll
    for (int ht = 0; ht < 4; ++ht) {
        int h = ht * 16 + mrow;
        short8 bl0 = *(const short8*)&Wl[h * HD + quad * 8];
        short8 bl1 = *(const short8*)&Wl[h * HD + 32 + quad * 8];
        short8 br0 = *(const short8*)&Wr[h * HD + quad * 8];
        short8 br1 = *(const short8*)&Wr[h * HD + 32 + quad * 8];
        floatx4 a = {0.f, 0.f, 0.f, 0.f};
        a = __builtin_amdgcn_mfma_f32_16x16x32_bf16(am0, bl0, a, 0, 0, 0);
        a = __builtin_amdgcn_mfma_f32_16x16x32_bf16(am1, bl1, a, 0, 0, 0);
        a = __builtin_amdgcn_mfma_f32_16x16x32_bf16(ax0, br0, a, 0, 0, 0);
        a = __builtin_amdgcn_mfma_f32_16x16x32_bf16(ax1, br1, a, 0, 0, 0);
        accv[ht] = a;
    }

    long base = (long)t0 * HD;
    #pragma unroll
    for (int ht = 0; ht < 4; ++ht) {
        int h = ht * 16 + mrow;
        float bv = lb[h];
        #pragma unroll
        for (int r = 0; r < 4; ++r) {
            int node = w * 16 + quad * 4 + r;
            float v = accv[ht][r] + bv;
            if (RELU) v = fmaxf(v, 0.0f);
            out[base + node * HD + h] = f2bf_raw(v);
        }
    }
}

// ---------------- final: out[e] = dot(x2[u[e]], x2[NU + m[e]])
// 4 lanes per edge, 16 edges per wave; 16B vector loads; 2-step xor reduce.
__global__ __launch_bounds__(256) void dot_kernel(
    const unsigned short* __restrict__ x2,
    const int* __restrict__ eli,
    void* __restrict__ out,
    int EL,
    const int* __restrict__ flags)
{
    int wid = (blockIdx.x * 256 + threadIdx.x) >> 6;    // global wave id
    long base = (long)wid * 16;                          // first edge of this wave
    if (base >= EL) return;
    int lane = threadIdx.x & 63;
    int isbf = flags[0];
    int is64 = flags[1];

    // lanes 0..15 load u indices, lanes 16..31 load m indices (EL % 16 == 0)
    int idxv = 0;
    if (lane < 16)      idxv = ldidx(eli, base + lane, is64);
    else if (lane < 32) idxv = ldidx(eli, (long)EL + base + (lane - 16), is64);

    int e   = lane >> 2;          // edge slot 0..15
    int seg = lane & 3;           // 16-element segment of the 64-dim row
    int u = __shfl(idxv, e);
    int m = __shfl(idxv, 16 + e);

    const short8* up = (const short8*)(x2 + (long)u * HD + seg * 16);
    const short8* mp = (const short8*)(x2 + (long)(NU + m) * HD + seg * 16);
    short8 a0 = up[0], a1 = up[1];
    short8 b0 = mp[0], b1 = mp[1];

    float p = 0.f;
    #pragma unroll
    for (int j = 0; j < 8; ++j) {
        p += bfu2f((unsigned short)a0[j]) * bfu2f((unsigned short)b0[j]);
        p += bfu2f((unsigned short)a1[j]) * bfu2f((unsigned short)b1[j]);
    }
    p += __shfl_xor(p, 1);
    p += __shfl_xor(p, 2);

    if (seg == 0) {
        long g = base + e;
        if (isbf) ((unsigned short*)out)[g] = f2bf_raw(p);
        else      ((float*)out)[g] = p;
    }
}

extern "C" void kernel_launch(void* const* d_in, const int* in_sizes, int n_in,
                              void* d_out, int out_size, void* d_ws, size_t ws_size,
                              hipStream_t stream)
{
    const void* movie_x   = d_in[0];
    const void* user_emb  = d_in[1];
    const void* movie_emb = d_in[2];
    const void* lin_W     = d_in[3];
    const void* lin_b     = d_in[4];
    const void* W1l       = d_in[5];
    const void* b1        = d_in[6];
    const void* W1r       = d_in[7];
    const void* W2l       = d_in[8];
    const void* b2        = d_in[9];
    const void* W2r       = d_in[10];
    const int* ei  = (const int*)d_in[11];
    const int* eli = (const int*)d_in[12];
    int E  = in_sizes[11] / 2;
    int EL = in_sizes[12] / 2;

    const int NB = (NT + 255) / 256;     // 1094 scan blocks

    char* w = (char*)d_ws;
    unsigned short* xb      = (unsigned short*)w;  w += (size_t)NT * HD * 2;  // 35.84 MB
    unsigned short* hb      = (unsigned short*)w;  w += (size_t)NT * HD * 2;  // 35.84 MB
    int*            cnt     = (int*)w;             w += (size_t)NT * 4;
    int*            rowptr  = (int*)w;             w += (size_t)NT * 4;
    int*            srclist = (int*)w;             w += (size_t)E * 4;        // 5 MB
    int*            packed  = (int*)w;             w += (size_t)E * 4;        // 5 MB
    unsigned char*  dloc    = (unsigned char*)w;   w += (size_t)E;            // 1.25 MB
    int*            bsum    = (int*)w;             w += (size_t)NB * 4;
    int*            bfill   = (int*)w;             w += (size_t)NBUCK * 4;
    unsigned short* wbuf    = (unsigned short*)w;  w += (size_t)16512 * 2;
    int*            flags   = (int*)w;

    unsigned short* w1l_b = wbuf;
    unsigned short* w1r_b = wbuf + 4096;
    unsigned short* w2l_b = wbuf + 8192;
    unsigned short* w2r_b = wbuf + 12288;
    unsigned short* b1_b  = wbuf + 16384;
    unsigned short* b2_b  = wbuf + 16448;

    const int user_blocks   = (NU * HD / 8) / 256;      // 6250 exactly
    const int movie_blocks  = (NM * 64 + 255) / 256;    // 20000 (wave per movie)
    const int edge_blocks   = (E + 255) / 256;
    const int bucket_blocks = (E + CHUNK - 1) / CHUNK;  // 153
    const int tile_blocks   = NT / 64;                  // 4375
    const int dot_blocks    = ((EL + 15) / 16 + 3) / 4; // 7813

    probe_kernel<<<1, 64, 0, stream>>>(user_emb, ei, flags);

    prep_user<<<user_blocks, 256, 0, stream>>>(user_emb, xb, flags);
    prep_movie<<<movie_blocks, 256, 0, stream>>>(movie_x, movie_emb, lin_W, lin_b, xb, flags);
    prep_w<<<(16512 + 255) / 256, 256, 0, stream>>>(W1l, W1r, W2l, W2r, b1, b2, wbuf, flags);

    // CSR build (once; reused by both layers)
    hipMemsetAsync(cnt, 0, (size_t)NT * 4, stream);
    hipMemsetAsync(bfill, 0, (size_t)NBUCK * 4, stream);
    hist_kernel<<<edge_blocks, 256, 0, stream>>>(ei, E, cnt, flags);
    scan1_kernel<<<NB, 256, 0, stream>>>(cnt, bsum);
    scan2_kernel<<<1, 256, 0, stream>>>(bsum, NB);
    scan3_kernel<<<NB, 256, 0, stream>>>(cnt, bsum, rowptr);
    bucket_kernel<<<bucket_blocks, 256, 0, stream>>>(ei, E, rowptr, bfill, packed, flags);
    finefill_kernel<<<NBUCK, 256, 0, stream>>>(rowptr, packed, srclist, dloc, E);

    // layer 1: xb -> hb   (fused gather+combine)
    sage_fused<true><<<tile_blocks, 256, 0, stream>>>(xb, rowptr, cnt, srclist, dloc,
                                                      w1l_b, b1_b, w1r_b, hb, E);
    // layer 2: hb -> xb
    sage_fused<false><<<tile_blocks, 256, 0, stream>>>(hb, rowptr, cnt, srclist, dloc,
                                                       w2l_b, b2_b, w2r_b, xb, E);

    // final edge dot products
    dot_kernel<<<dot_blocks, 256, 0, stream>>>(xb, eli, d_out, EL, flags);
}

// Round 10
// 433.960 us; speedup vs baseline: 2.7504x; 2.7504x over previous
//
#include <hip/hip_runtime.h>
#include <hip/hip_bf16.h>

#define NU 200000
#define NM 80000
#define NT 280000   // NU + NM
#define HD 64
#define FM 20

#define BSHIFT 10
#define NBUCK ((NT + 1023) >> 10)   // 274 buckets of 1024 nodes
#define CHUNK 8192

typedef __attribute__((ext_vector_type(8))) short short8;
typedef __attribute__((ext_vector_type(4))) float floatx4;

__device__ __forceinline__ float bfu2f(unsigned short u) {
    union { unsigned int u; float f; } c; c.u = ((unsigned int)u) << 16; return c.f;
}

__device__ __forceinline__ unsigned short f2bf_raw(float f) {
    union { float f; unsigned int u; } c; c.f = f;
    unsigned int u = c.u + 0x7FFFu + ((c.u >> 16) & 1u);   // round-nearest-even
    return (unsigned short)(u >> 16);
}

__device__ __forceinline__ float ldf(const void* p, long i, int isbf) {
    return isbf ? bfu2f(((const unsigned short*)p)[i]) : ((const float*)p)[i];
}
__device__ __forceinline__ int ldidx(const int* p, long j, int is64) {
    return is64 ? p[2 * j] : p[j];
}

// ---------------- runtime dtype probe -> flags[0]=isbf16, flags[1]=isint64
__global__ void probe_kernel(const void* user_emb, const int* ei, int* flags) {
    int t = threadIdx.x;
    int bad = 0;
    for (int i = t; i < 128; i += 64) {
        unsigned short h = ((const unsigned short*)user_emb)[i];
        unsigned int e = (h >> 7) & 0xFF;
        if (e >= 135) bad = 1;               // |x| >= 256, or Inf/NaN -> not real bf16
    }
    unsigned long long mf = __ballot(bad != 0);
    int odd_nonzero = 0;
    if (t < 16 && ei[2 * t + 1] != 0) odd_nonzero = 1;
    unsigned long long mi = __ballot(odd_nonzero != 0);
    if (t == 0) {
        flags[0] = (mf == 0) ? 1 : 0;
        flags[1] = (mi == 0) ? 1 : 0;
    }
}

// ---------------- prep A: user rows, vectorized copy/convert (8 elems/thread)
__global__ __launch_bounds__(256) void prep_user(
    const void* __restrict__ user_emb,
    unsigned short* __restrict__ xb,
    const int* __restrict__ flags)
{
    long t = (long)blockIdx.x * 256 + threadIdx.x;        // t < NU*HD/8 = 1.6M exactly
    int isbf = flags[0];
    if (isbf) {
        ((short8*)xb)[t] = ((const short8*)user_emb)[t];
    } else {
        floatx4 a = ((const floatx4*)user_emb)[2 * t];
        floatx4 b = ((const floatx4*)user_emb)[2 * t + 1];
        short8 r;
        r[0] = (short)f2bf_raw(a[0]); r[1] = (short)f2bf_raw(a[1]);
        r[2] = (short)f2bf_raw(a[2]); r[3] = (short)f2bf_raw(a[3]);
        r[4] = (short)f2bf_raw(b[0]); r[5] = (short)f2bf_raw(b[1]);
        r[6] = (short)f2bf_raw(b[2]); r[7] = (short)f2bf_raw(b[3]);
        ((short8*)xb)[t] = r;
    }
}

// ---------------- prep B: movie rows. lin_W transposed in LDS; movie_x row via shfl.
__global__ __launch_bounds__(256) void prep_movie(
    const void* __restrict__ movie_x,
    const void* __restrict__ movie_emb,
    const void* __restrict__ lin_W,
    const void* __restrict__ lin_b,
    unsigned short* __restrict__ xb,
    const int* __restrict__ flags)
{
    __shared__ float lWT[FM * HD];   // [k][h] layout -> conflict-free reads
    __shared__ float lb[HD];
    int tid = threadIdx.x;
    int isbf = flags[0];
    for (int i = tid; i < FM * HD; i += 256) {
        int k = i >> 6, h = i & 63;
        lWT[i] = ldf(lin_W, (long)h * FM + k, isbf);
    }
    if (tid < HD) lb[tid] = ldf(lin_b, tid, isbf);
    __syncthreads();

    int m = (blockIdx.x * 256 + tid) >> 6;    // movie id, one wave per movie
    int lane = tid & 63;
    if (m >= NM) return;
    float mxv = (lane < FM) ? ldf(movie_x, (long)m * FM + lane, isbf) : 0.f;
    float acc = lb[lane] + ldf(movie_emb, (long)m * HD + lane, isbf);
    #pragma unroll
    for (int k = 0; k < FM; ++k)
        acc += __shfl(mxv, k) * lWT[k * HD + lane];
    xb[(long)(NU + m) * HD + lane] = f2bf_raw(acc);
}

// ---------------- CSR build ----------------
__global__ __launch_bounds__(256) void hist_kernel(
    const int* __restrict__ ei, int E, int* __restrict__ cnt, const int* __restrict__ flags)
{
    long e = (long)blockIdx.x * 256 + threadIdx.x;
    if (e >= E) return;
    int d = ldidx(ei, (long)E + e, flags[1]);
    atomicAdd(&cnt[d], 1);
}

__global__ __launch_bounds__(256) void scan1_kernel(const int* __restrict__ cnt, int* __restrict__ bsum)
{
    __shared__ int s[256];
    int t = threadIdx.x;
    long i = (long)blockIdx.x * 256 + t;
    s[t] = (i < NT) ? cnt[i] : 0;
    __syncthreads();
    for (int off = 128; off > 0; off >>= 1) {
        if (t < off) s[t] += s[t + off];
        __syncthreads();
    }
    if (t == 0) bsum[blockIdx.x] = s[0];
}

__global__ __launch_bounds__(256) void scan2_kernel(int* __restrict__ bsum, int NB)
{
    __shared__ int chunk[256];
    int t = threadIdx.x;
    int per = (NB + 255) / 256;
    int begin = t * per;
    int end = begin + per; if (end > NB) end = NB; if (begin > NB) begin = NB;
    int sum = 0;
    for (int i = begin; i < end; ++i) sum += bsum[i];
    chunk[t] = sum;
    __syncthreads();
    for (int off = 1; off < 256; off <<= 1) {
        int v = chunk[t];
        if (t >= off) v += chunk[t - off];
        __syncthreads();
        chunk[t] = v;
        __syncthreads();
    }
    int run = (t == 0) ? 0 : chunk[t - 1];
    for (int i = begin; i < end; ++i) {
        int v = bsum[i];
        bsum[i] = run;
        run += v;
    }
}

__global__ __launch_bounds__(256) void scan3_kernel(
    const int* __restrict__ cnt, const int* __restrict__ bsum,
    int* __restrict__ rowptr)
{
    __shared__ int s[256];
    int t = threadIdx.x;
    long i = (long)blockIdx.x * 256 + t;
    int v = (i < NT) ? cnt[i] : 0;
    s[t] = v;
    __syncthreads();
    for (int off = 1; off < 256; off <<= 1) {
        int u = s[t];
        if (t >= off) u += s[t - off];
        __syncthreads();
        s[t] = u;
        __syncthreads();
    }
    if (i < NT) rowptr[i] = bsum[blockIdx.x] + s[t] - v;   // exclusive
}

// ---------------- bucket pass: group edges by dst>>10 into packed buffer (coalesced runs)
// packed entry: (src << 10) | (dst & 1023); bucket b's region = [rowptr[b<<10], ...)
__global__ __launch_bounds__(256) void bucket_kernel(
    const int* __restrict__ ei, int E,
    const int* __restrict__ rowptr,
    int* __restrict__ bfill,           // NBUCK cursors, pre-zeroed
    int* __restrict__ packed,
    const int* __restrict__ flags)
{
    __shared__ int hist[NBUCK];
    __shared__ int loff[NBUCK + 1];
    __shared__ int cur[NBUCK];
    __shared__ int wbase[NBUCK];
    __shared__ int stage[CHUNK];

    int tid = threadIdx.x;
    int is64 = flags[1];
    long e0 = (long)blockIdx.x * CHUNK;
    long rem = (long)E - e0;
    int n = (rem < CHUNK) ? (int)rem : CHUNK;
    if (n <= 0) return;

    for (int i = tid; i < NBUCK; i += 256) { hist[i] = 0; cur[i] = 0; }
    __syncthreads();
    for (int j = tid; j < n; j += 256) {
        int d = ldidx(ei, (long)E + e0 + j, is64);
        atomicAdd(&hist[d >> BSHIFT], 1);
    }
    __syncthreads();
    if (tid == 0) {                      // serial excl-scan over 274 entries (cheap)
        int run = 0;
        for (int b = 0; b < NBUCK; ++b) { loff[b] = run; run += hist[b]; }
        loff[NBUCK] = run;
    }
    __syncthreads();
    for (int b = tid; b < NBUCK; b += 256) {
        int h = hist[b];
        int g = (h > 0) ? atomicAdd(&bfill[b], h) : 0;
        wbase[b] = rowptr[b << BSHIFT] + g - loff[b];
    }
    __syncthreads();
    for (int j = tid; j < n; j += 256) {
        int s = ldidx(ei, e0 + j, is64);
        int d = ldidx(ei, (long)E + e0 + j, is64);
        int b = d >> BSHIFT;
        int lpos = loff[b] + atomicAdd(&cur[b], 1);
        stage[lpos] = (s << BSHIFT) | (d & ((1 << BSHIFT) - 1));
    }
    __syncthreads();
    for (int j = tid; j < n; j += 256) {
        int lo = 0, hi = NBUCK;          // find b: loff[b] <= j < loff[b+1]
        while (hi - lo > 1) { int mid = (lo + hi) >> 1; if (loff[mid] <= j) lo = mid; else hi = mid; }
        packed[wbase[lo] + j] = stage[j];
    }
}

// ---------------- fine fill: one block per bucket; all scattered stores confined to one ~18KB region
__global__ __launch_bounds__(256) void finefill_kernel(
    const int* __restrict__ rowptr,
    const int* __restrict__ packed,
    int* __restrict__ srclist,
    int E)
{
    __shared__ int lfill[1 << BSHIFT];
    int b = blockIdx.x;
    int tid = threadIdx.x;
    int nbase = b << BSHIFT;
    int nend = nbase + (1 << BSHIFT); if (nend > NT) nend = NT;
    int nloc = nend - nbase;
    for (int i = tid; i < nloc; i += 256) lfill[i] = rowptr[nbase + i];
    __syncthreads();
    int beg = rowptr[nbase];
    int end = (nend < NT) ? rowptr[nend] : E;
    for (int j = beg + tid; j < end; j += 256) {
        int p = packed[j];
        int dl = p & ((1 << BSHIFT) - 1);
        int pos = atomicAdd(&lfill[dl], 1);
        srclist[pos] = p >> BSHIFT;
    }
}

// ---------------- gather: meanb[n] = mean over incoming edges of x[src]
// 4 lanes per node, 16 nodes per wave. Lane owns a fixed 16-elem (32B) segment of
// its node's row => no cross-lane reduction; 16 independent load chains per wave.
__global__ __launch_bounds__(256) void gather_mean(
    const unsigned short* __restrict__ x,
    const int* __restrict__ rowptr,
    const int* __restrict__ cnt,
    const int* __restrict__ srclist,
    unsigned short* __restrict__ meanb)
{
    int wid = (blockIdx.x * 256 + threadIdx.x) >> 6;   // wave id; NT = 17500*16 exactly
    int lane = threadIdx.x & 63;
    int g = lane >> 2;          // node group 0..15
    int sub = lane & 3;         // 16-elem segment 0..3
    int n = wid * 16 + g;
    if (n >= NT) return;
    int beg = rowptr[n];
    int deg = cnt[n];

    float acc[16];
    #pragma unroll
    for (int k = 0; k < 16; ++k) acc[k] = 0.f;

    for (int j0 = 0; j0 < deg; j0 += 4) {
        int e = j0 + sub;
        int sv = (e < deg) ? srclist[beg + e] : 0;    // 4 coalesced edge-id loads per group
        int cq = deg - j0; if (cq > 4) cq = 4;
        short8 r[4][2];
        #pragma unroll
        for (int q = 0; q < 4; ++q) {                 // 8 independent 16B loads in flight
            int s = __shfl(sv, (g << 2) | q);
            const short8* p = (const short8*)&x[(long)s * HD + sub * 16];
            r[q][0] = p[0];
            r[q][1] = p[1];
        }
        #pragma unroll
        for (int q = 0; q < 4; ++q) {
            if (q < cq) {
                #pragma unroll
                for (int k = 0; k < 8; ++k) {
                    acc[k]     += bfu2f((unsigned short)r[q][0][k]);
                    acc[k + 8] += bfu2f((unsigned short)r[q][1][k]);
                }
            }
        }
    }

    float rd = 1.0f / fmaxf((float)deg, 1.0f);
    short8 o0, o1;
    #pragma unroll
    for (int k = 0; k < 8; ++k) {
        o0[k] = (short)f2bf_raw(acc[k] * rd);
        o1[k] = (short)f2bf_raw(acc[k + 8] * rd);
    }
    short8* op = (short8*)&meanb[(long)n * HD + sub * 16];
    op[0] = o0;
    op[1] = o1;
}

// ---------------- combine: out = act( mean @ Wl.T + b + xin @ Wr.T )   [in-place: out may == xin]
template <bool RELU>
__global__ __launch_bounds__(256) void combine_kernel(
    const unsigned short* __restrict__ meanb,
    const unsigned short* __restrict__ xin,
    const void* __restrict__ Wl,
    const void* __restrict__ bias,
    const void* __restrict__ Wr,
    unsigned short* __restrict__ out,
    const int* __restrict__ flags)
{
    __shared__ short8 lWl8[HD * HD / 8];
    __shared__ short8 lWr8[HD * HD / 8];
    __shared__ short8 lmean8[HD * HD / 8];
    __shared__ short8 lx8[HD * HD / 8];
    __shared__ float lb[HD];
    unsigned short* lWl  = (unsigned short*)lWl8;
    unsigned short* lWr  = (unsigned short*)lWr8;
    unsigned short* lmean = (unsigned short*)lmean8;
    unsigned short* lx   = (unsigned short*)lx8;

    int tid = threadIdx.x;
    int isbf = flags[0];
    if (isbf) {
        const short8* wl8 = (const short8*)Wl;
        const short8* wr8 = (const short8*)Wr;
        for (int i = tid; i < HD * HD / 8; i += 256) { lWl8[i] = wl8[i]; lWr8[i] = wr8[i]; }
    } else {
        const floatx4* wlf = (const floatx4*)Wl;
        const floatx4* wrf = (const floatx4*)Wr;
        for (int i = tid; i < HD * HD / 8; i += 256) {
            floatx4 a = wlf[2 * i], b = wlf[2 * i + 1];
            short8 r;
            r[0]=(short)f2bf_raw(a[0]); r[1]=(short)f2bf_raw(a[1]); r[2]=(short)f2bf_raw(a[2]); r[3]=(short)f2bf_raw(a[3]);
            r[4]=(short)f2bf_raw(b[0]); r[5]=(short)f2bf_raw(b[1]); r[6]=(short)f2bf_raw(b[2]); r[7]=(short)f2bf_raw(b[3]);
            lWl8[i] = r;
            a = wrf[2 * i]; b = wrf[2 * i + 1];
            r[0]=(short)f2bf_raw(a[0]); r[1]=(short)f2bf_raw(a[1]); r[2]=(short)f2bf_raw(a[2]); r[3]=(short)f2bf_raw(a[3]);
            r[4]=(short)f2bf_raw(b[0]); r[5]=(short)f2bf_raw(b[1]); r[6]=(short)f2bf_raw(b[2]); r[7]=(short)f2bf_raw(b[3]);
            lWr8[i] = r;
        }
    }
    if (tid < HD) lb[tid] = ldf(bias, tid, isbf);

    int tile = blockIdx.x;                 // 64 nodes per tile; NT = 64*4375 exactly
    long base = (long)tile * HD * HD;
    const short8* mv = (const short8*)(meanb + base);
    const short8* xv = (const short8*)(xin + base);
    for (int i = tid; i < HD * HD / 8; i += 256) { lmean8[i] = mv[i]; lx8[i] = xv[i]; }
    __syncthreads();      // all reads of this tile's xin complete before any in-place write below

    int w = tid >> 6;
    int lane = tid & 63;
    int mrow = lane & 15;
    int quad = lane >> 4;

    short8 am0 = *(const short8*)&lmean[(w * 16 + mrow) * HD + quad * 8];
    short8 am1 = *(const short8*)&lmean[(w * 16 + mrow) * HD + 32 + quad * 8];
    short8 ax0 = *(const short8*)&lx[(w * 16 + mrow) * HD + quad * 8];
    short8 ax1 = *(const short8*)&lx[(w * 16 + mrow) * HD + 32 + quad * 8];

    floatx4 acc[4];
    #pragma unroll
    for (int ht = 0; ht < 4; ++ht) {
        int h = ht * 16 + mrow;
        short8 bl0 = *(const short8*)&lWl[h * HD + quad * 8];
        short8 bl1 = *(const short8*)&lWl[h * HD + 32 + quad * 8];
        short8 br0 = *(const short8*)&lWr[h * HD + quad * 8];
        short8 br1 = *(const short8*)&lWr[h * HD + 32 + quad * 8];
        floatx4 a = {0.f, 0.f, 0.f, 0.f};
        a = __builtin_amdgcn_mfma_f32_16x16x32_bf16(am0, bl0, a, 0, 0, 0);
        a = __builtin_amdgcn_mfma_f32_16x16x32_bf16(am1, bl1, a, 0, 0, 0);
        a = __builtin_amdgcn_mfma_f32_16x16x32_bf16(ax0, br0, a, 0, 0, 0);
        a = __builtin_amdgcn_mfma_f32_16x16x32_bf16(ax1, br1, a, 0, 0, 0);
        acc[ht] = a;
    }

    #pragma unroll
    for (int ht = 0; ht < 4; ++ht) {
        int h = ht * 16 + mrow;
        float bv = lb[h];
        #pragma unroll
        for (int r = 0; r < 4; ++r) {
            int node = w * 16 + quad * 4 + r;
            float v = acc[ht][r] + bv;
            if (RELU) v = fmaxf(v, 0.0f);
            out[base + node * HD + h] = f2bf_raw(v);
        }
    }
}

// ---------------- final: out[e] = dot(x2[u[e]], x2[NU + m[e]])
// 4 lanes per edge, 16 edges per wave; 16B vector loads; 2-step xor reduce.
__global__ __launch_bounds__(256) void dot_kernel(
    const unsigned short* __restrict__ x2,
    const int* __restrict__ eli,
    void* __restrict__ out,
    int EL,
    const int* __restrict__ flags)
{
    int wid = (blockIdx.x * 256 + threadIdx.x) >> 6;    // global wave id
    long base = (long)wid * 16;                          // first edge of this wave
    if (base >= EL) return;
    int lane = threadIdx.x & 63;
    int isbf = flags[0];
    int is64 = flags[1];

    // lanes 0..15 load u indices, lanes 16..31 load m indices (EL % 16 == 0)
    int idxv = 0;
    if (lane < 16)      idxv = ldidx(eli, base + lane, is64);
    else if (lane < 32) idxv = ldidx(eli, (long)EL + base + (lane - 16), is64);

    int e   = lane >> 2;          // edge slot 0..15
    int seg = lane & 3;           // 16-element segment of the 64-dim row
    int u = __shfl(idxv, e);
    int m = __shfl(idxv, 16 + e);

    const short8* up = (const short8*)(x2 + (long)u * HD + seg * 16);
    const short8* mp = (const short8*)(x2 + (long)(NU + m) * HD + seg * 16);
    short8 a0 = up[0], a1 = up[1];
    short8 b0 = mp[0], b1 = mp[1];

    float p = 0.f;
    #pragma unroll
    for (int j = 0; j < 8; ++j) {
        p += bfu2f((unsigned short)a0[j]) * bfu2f((unsigned short)b0[j]);
        p += bfu2f((unsigned short)a1[j]) * bfu2f((unsigned short)b1[j]);
    }
    p += __shfl_xor(p, 1);
    p += __shfl_xor(p, 2);

    if (seg == 0) {
        long g = base + e;
        if (isbf) ((unsigned short*)out)[g] = f2bf_raw(p);
        else      ((float*)out)[g] = p;
    }
}

extern "C" void kernel_launch(void* const* d_in, const int* in_sizes, int n_in,
                              void* d_out, int out_size, void* d_ws, size_t ws_size,
                              hipStream_t stream)
{
    const void* movie_x   = d_in[0];
    const void* user_emb  = d_in[1];
    const void* movie_emb = d_in[2];
    const void* lin_W     = d_in[3];
    const void* lin_b     = d_in[4];
    const void* W1l       = d_in[5];
    const void* b1        = d_in[6];
    const void* W1r       = d_in[7];
    const void* W2l       = d_in[8];
    const void* b2        = d_in[9];
    const void* W2r       = d_in[10];
    const int* ei  = (const int*)d_in[11];
    const int* eli = (const int*)d_in[12];
    int E  = in_sizes[11] / 2;
    int EL = in_sizes[12] / 2;

    const int NB = (NT + 255) / 256;     // 1094 scan blocks

    char* w = (char*)d_ws;
    unsigned short* xb      = (unsigned short*)w;  w += (size_t)NT * HD * 2;  // 35.84 MB
    unsigned short* meanb   = (unsigned short*)w;  w += (size_t)NT * HD * 2;  // 35.84 MB
    int*            cnt     = (int*)w;             w += (size_t)NT * 4;
    int*            rowptr  = (int*)w;             w += (size_t)NT * 4;
    int*            srclist = (int*)w;             w += (size_t)E * 4;        // 5 MB
    int*            packed  = (int*)w;             w += (size_t)E * 4;        // 5 MB
    int*            bsum    = (int*)w;             w += (size_t)NB * 4;
    int*            bfill   = (int*)w;             w += (size_t)NBUCK * 4;
    int*            flags   = (int*)w;

    const int user_blocks   = (NU * HD / 8) / 256;      // 6250 exactly
    const int movie_blocks  = (NM * 64 + 255) / 256;    // 20000 (wave per movie)
    const int edge_blocks   = (E + 255) / 256;
    const int bucket_blocks = (E + CHUNK - 1) / CHUNK;  // 153
    const int gather_blocks = ((NT / 16) * 64 + 255) / 256;  // 4375 (16 nodes/wave)
    const int tile_blocks   = NT / 64;                  // 4375
    const int dot_blocks    = ((EL + 15) / 16 + 3) / 4; // 7813

    probe_kernel<<<1, 64, 0, stream>>>(user_emb, ei, flags);

    prep_user<<<user_blocks, 256, 0, stream>>>(user_emb, xb, flags);
    prep_movie<<<movie_blocks, 256, 0, stream>>>(movie_x, movie_emb, lin_W, lin_b, xb, flags);

    // CSR build (once; reused by both layers)
    hipMemsetAsync(cnt, 0, (size_t)NT * 4, stream);
    hipMemsetAsync(bfill, 0, (size_t)NBUCK * 4, stream);
    hist_kernel<<<edge_blocks, 256, 0, stream>>>(ei, E, cnt, flags);
    scan1_kernel<<<NB, 256, 0, stream>>>(cnt, bsum);
    scan2_kernel<<<1, 256, 0, stream>>>(bsum, NB);
    scan3_kernel<<<NB, 256, 0, stream>>>(cnt, bsum, rowptr);
    bucket_kernel<<<bucket_blocks, 256, 0, stream>>>(ei, E, rowptr, bfill, packed, flags);
    finefill_kernel<<<NBUCK, 256, 0, stream>>>(rowptr, packed, srclist, E);

    // layer 1
    gather_mean<<<gather_blocks, 256, 0, stream>>>(xb, rowptr, cnt, srclist, meanb);
    combine_kernel<true><<<tile_blocks, 256, 0, stream>>>(meanb, xb, W1l, b1, W1r, xb, flags);

    // layer 2
    gather_mean<<<gather_blocks, 256, 0, stream>>>(xb, rowptr, cnt, srclist, meanb);
    combine_kernel<false><<<tile_blocks, 256, 0, stream>>>(meanb, xb, W2l, b2, W2r, xb, flags);

    // final edge dot products
    dot_kernel<<<dot_blocks, 256, 0, stream>>>(xb, eli, d_out, EL, flags);
}

// Round 11
// 419.647 us; speedup vs baseline: 2.8442x; 1.0341x over previous
//
#include <hip/hip_runtime.h>
#include <hip/hip_bf16.h>

#define NU 200000
#define NM 80000
#define NT 280000   // NU + NM
#define HD 64
#define FM 20

#define BSHIFT 10
#define NBUCK ((NT + 1023) >> 10)   // 274 buckets of 1024 nodes
#define CHUNK 2048                  // edges per bucket block (611 blocks)

typedef __attribute__((ext_vector_type(8))) short short8;
typedef __attribute__((ext_vector_type(4))) float floatx4;

__device__ __forceinline__ float bfu2f(unsigned short u) {
    union { unsigned int u; float f; } c; c.u = ((unsigned int)u) << 16; return c.f;
}

__device__ __forceinline__ unsigned short f2bf_raw(float f) {
    union { float f; unsigned int u; } c; c.f = f;
    unsigned int u = c.u + 0x7FFFu + ((c.u >> 16) & 1u);   // round-nearest-even
    return (unsigned short)(u >> 16);
}

__device__ __forceinline__ float ldf(const void* p, long i, int isbf) {
    return isbf ? bfu2f(((const unsigned short*)p)[i]) : ((const float*)p)[i];
}
__device__ __forceinline__ int ldidx(const int* p, long j, int is64) {
    return is64 ? p[2 * j] : p[j];
}

// ---------------- runtime dtype probe -> flags[0]=isbf16, flags[1]=isint64
__global__ void probe_kernel(const void* user_emb, const int* ei, int* flags) {
    int t = threadIdx.x;
    int bad = 0;
    for (int i = t; i < 128; i += 64) {
        unsigned short h = ((const unsigned short*)user_emb)[i];
        unsigned int e = (h >> 7) & 0xFF;
        if (e >= 135) bad = 1;               // |x| >= 256, or Inf/NaN -> not real bf16
    }
    unsigned long long mf = __ballot(bad != 0);
    int odd_nonzero = 0;
    if (t < 16 && ei[2 * t + 1] != 0) odd_nonzero = 1;
    unsigned long long mi = __ballot(odd_nonzero != 0);
    if (t == 0) {
        flags[0] = (mf == 0) ? 1 : 0;
        flags[1] = (mi == 0) ? 1 : 0;
    }
}

// ---------------- prep A: user rows, vectorized copy/convert (8 elems/thread)
__global__ __launch_bounds__(256) void prep_user(
    const void* __restrict__ user_emb,
    unsigned short* __restrict__ xb,
    const int* __restrict__ flags)
{
    long t = (long)blockIdx.x * 256 + threadIdx.x;        // t < NU*HD/8 = 1.6M exactly
    int isbf = flags[0];
    if (isbf) {
        ((short8*)xb)[t] = ((const short8*)user_emb)[t];
    } else {
        floatx4 a = ((const floatx4*)user_emb)[2 * t];
        floatx4 b = ((const floatx4*)user_emb)[2 * t + 1];
        short8 r;
        r[0] = (short)f2bf_raw(a[0]); r[1] = (short)f2bf_raw(a[1]);
        r[2] = (short)f2bf_raw(a[2]); r[3] = (short)f2bf_raw(a[3]);
        r[4] = (short)f2bf_raw(b[0]); r[5] = (short)f2bf_raw(b[1]);
        r[6] = (short)f2bf_raw(b[2]); r[7] = (short)f2bf_raw(b[3]);
        ((short8*)xb)[t] = r;
    }
}

// ---------------- prep B: movie rows. lin_W transposed in LDS; movie_x row via shfl.
__global__ __launch_bounds__(256) void prep_movie(
    const void* __restrict__ movie_x,
    const void* __restrict__ movie_emb,
    const void* __restrict__ lin_W,
    const void* __restrict__ lin_b,
    unsigned short* __restrict__ xb,
    const int* __restrict__ flags)
{
    __shared__ float lWT[FM * HD];   // [k][h] layout -> conflict-free reads
    __shared__ float lb[HD];
    int tid = threadIdx.x;
    int isbf = flags[0];
    for (int i = tid; i < FM * HD; i += 256) {
        int k = i >> 6, h = i & 63;
        lWT[i] = ldf(lin_W, (long)h * FM + k, isbf);
    }
    if (tid < HD) lb[tid] = ldf(lin_b, tid, isbf);
    __syncthreads();

    int m = (blockIdx.x * 256 + tid) >> 6;    // movie id, one wave per movie
    int lane = tid & 63;
    if (m >= NM) return;
    float mxv = (lane < FM) ? ldf(movie_x, (long)m * FM + lane, isbf) : 0.f;
    float acc = lb[lane] + ldf(movie_emb, (long)m * HD + lane, isbf);
    #pragma unroll
    for (int k = 0; k < FM; ++k)
        acc += __shfl(mxv, k) * lWT[k * HD + lane];
    xb[(long)(NU + m) * HD + lane] = f2bf_raw(acc);
}

// ---------------- CSR build ----------------
__global__ __launch_bounds__(256) void hist_kernel(
    const int* __restrict__ ei, int E, int* __restrict__ cnt, const int* __restrict__ flags)
{
    long e = (long)blockIdx.x * 256 + threadIdx.x;
    if (e >= E) return;
    int d = ldidx(ei, (long)E + e, flags[1]);
    atomicAdd(&cnt[d], 1);
}

__global__ __launch_bounds__(256) void scan1_kernel(const int* __restrict__ cnt, int* __restrict__ bsum)
{
    __shared__ int s[256];
    int t = threadIdx.x;
    long i = (long)blockIdx.x * 256 + t;
    s[t] = (i < NT) ? cnt[i] : 0;
    __syncthreads();
    for (int off = 128; off > 0; off >>= 1) {
        if (t < off) s[t] += s[t + off];
        __syncthreads();
    }
    if (t == 0) bsum[blockIdx.x] = s[0];
}

__global__ __launch_bounds__(256) void scan2_kernel(int* __restrict__ bsum, int NB)
{
    __shared__ int chunk[256];
    int t = threadIdx.x;
    int per = (NB + 255) / 256;
    int begin = t * per;
    int end = begin + per; if (end > NB) end = NB; if (begin > NB) begin = NB;
    int sum = 0;
    for (int i = begin; i < end; ++i) sum += bsum[i];
    chunk[t] = sum;
    __syncthreads();
    for (int off = 1; off < 256; off <<= 1) {
        int v = chunk[t];
        if (t >= off) v += chunk[t - off];
        __syncthreads();
        chunk[t] = v;
        __syncthreads();
    }
    int run = (t == 0) ? 0 : chunk[t - 1];
    for (int i = begin; i < end; ++i) {
        int v = bsum[i];
        bsum[i] = run;
        run += v;
    }
}

__global__ __launch_bounds__(256) void scan3_kernel(
    const int* __restrict__ cnt, const int* __restrict__ bsum,
    int* __restrict__ rowptr)
{
    __shared__ int s[256];
    int t = threadIdx.x;
    long i = (long)blockIdx.x * 256 + t;
    int v = (i < NT) ? cnt[i] : 0;
    s[t] = v;
    __syncthreads();
    for (int off = 1; off < 256; off <<= 1) {
        int u = s[t];
        if (t >= off) u += s[t - off];
        __syncthreads();
        s[t] = u;
        __syncthreads();
    }
    if (i < NT) rowptr[i] = bsum[blockIdx.x] + s[t] - v;   // exclusive
}

// ---------------- bucket pass v2: group edges by dst>>10 into packed (direct write)
// per-wave histograms (low contention), parallel per-bucket wave-prefix (no serial
// scan), no stage / no binary search. packed entry: (src<<10) | (dst&1023).
__global__ __launch_bounds__(256) void bucket_kernel(
    const int* __restrict__ ei, int E,
    const int* __restrict__ rowptr,
    int* __restrict__ bfill,           // NBUCK global cursors, pre-zeroed
    int* __restrict__ packed,
    const int* __restrict__ flags)
{
    __shared__ int histw[4][NBUCK];    // per-wave histogram, then wave-exclusive prefix
    __shared__ int curw[4][NBUCK];     // per-wave running cursor (pass B)
    __shared__ int wbase[NBUCK];       // global base for this block's run in bucket b

    int tid = threadIdx.x;
    int w = tid >> 6;
    int lane = tid & 63;
    int is64 = flags[1];
    long e0 = (long)blockIdx.x * CHUNK;
    long rem = (long)E - e0;
    int n = (rem < CHUNK) ? (int)rem : CHUNK;
    if (n <= 0) return;

    for (int i = tid; i < NBUCK; i += 256) {
        histw[0][i] = 0; histw[1][i] = 0; histw[2][i] = 0; histw[3][i] = 0;
        curw[0][i] = 0;  curw[1][i] = 0;  curw[2][i] = 0;  curw[3][i] = 0;
    }
    __syncthreads();

    // pass A: per-wave histogram (wave w owns edges [w*512, min((w+1)*512, n)))
    int jbeg = w * (CHUNK / 4);
    int jend = jbeg + (CHUNK / 4); if (jend > n) jend = n;
    for (int j = jbeg + lane; j < jend; j += 64) {
        int d = ldidx(ei, (long)E + e0 + j, is64);
        atomicAdd(&histw[w][d >> BSHIFT], 1);
    }
    __syncthreads();

    // reserve global runs + wave-exclusive prefix per bucket (parallel over buckets)
    for (int b = tid; b < NBUCK; b += 256) {
        int h0 = histw[0][b], h1 = histw[1][b], h2 = histw[2][b], h3 = histw[3][b];
        int hb = h0 + h1 + h2 + h3;
        int g = (hb > 0) ? atomicAdd(&bfill[b], hb) : 0;
        wbase[b] = rowptr[b << BSHIFT] + g;
        histw[0][b] = 0;
        histw[1][b] = h0;
        histw[2][b] = h0 + h1;
        histw[3][b] = h0 + h1 + h2;
    }
    __syncthreads();

    // pass B: direct write to packed (block-exclusive runs per bucket)
    for (int j = jbeg + lane; j < jend; j += 64) {
        int s = ldidx(ei, e0 + j, is64);
        int d = ldidx(ei, (long)E + e0 + j, is64);
        int b = d >> BSHIFT;
        int pos = atomicAdd(&curw[w][b], 1);
        packed[wbase[b] + histw[w][b] + pos] = (s << BSHIFT) | (d & ((1 << BSHIFT) - 1));
    }
}

// ---------------- fine fill: one block per bucket; all scattered stores confined to one ~18KB region
__global__ __launch_bounds__(256) void finefill_kernel(
    const int* __restrict__ rowptr,
    const int* __restrict__ packed,
    int* __restrict__ srclist,
    int E)
{
    __shared__ int lfill[1 << BSHIFT];
    int b = blockIdx.x;
    int tid = threadIdx.x;
    int nbase = b << BSHIFT;
    int nend = nbase + (1 << BSHIFT); if (nend > NT) nend = NT;
    int nloc = nend - nbase;
    for (int i = tid; i < nloc; i += 256) lfill[i] = rowptr[nbase + i];
    __syncthreads();
    int beg = rowptr[nbase];
    int end = (nend < NT) ? rowptr[nend] : E;
    for (int j = beg + tid; j < end; j += 256) {
        int p = packed[j];
        int dl = p & ((1 << BSHIFT) - 1);
        int pos = atomicAdd(&lfill[dl], 1);
        srclist[pos] = p >> BSHIFT;
    }
}

// ---------------- gather: meanb[n] = mean over incoming edges of x[src]
// 4 lanes per node, 16 nodes per wave. Lane owns a fixed 16-elem (32B) segment of
// its node's row => no cross-lane reduction; 16 independent load chains per wave.
__global__ __launch_bounds__(256) void gather_mean(
    const unsigned short* __restrict__ x,
    const int* __restrict__ rowptr,
    const int* __restrict__ cnt,
    const int* __restrict__ srclist,
    unsigned short* __restrict__ meanb)
{
    int wid = (blockIdx.x * 256 + threadIdx.x) >> 6;   // wave id; NT = 17500*16 exactly
    int lane = threadIdx.x & 63;
    int g = lane >> 2;          // node group 0..15
    int sub = lane & 3;         // 16-elem segment 0..3
    int n = wid * 16 + g;
    if (n >= NT) return;
    int beg = rowptr[n];
    int deg = cnt[n];

    float acc[16];
    #pragma unroll
    for (int k = 0; k < 16; ++k) acc[k] = 0.f;

    for (int j0 = 0; j0 < deg; j0 += 4) {
        int e = j0 + sub;
        int sv = (e < deg) ? srclist[beg + e] : 0;    // 4 coalesced edge-id loads per group
        int cq = deg - j0; if (cq > 4) cq = 4;
        short8 r[4][2];
        #pragma unroll
        for (int q = 0; q < 4; ++q) {                 // 8 independent 16B loads in flight
            int s = __shfl(sv, (g << 2) | q);
            const short8* p = (const short8*)&x[(long)s * HD + sub * 16];
            r[q][0] = p[0];
            r[q][1] = p[1];
        }
        #pragma unroll
        for (int q = 0; q < 4; ++q) {
            if (q < cq) {
                #pragma unroll
                for (int k = 0; k < 8; ++k) {
                    acc[k]     += bfu2f((unsigned short)r[q][0][k]);
                    acc[k + 8] += bfu2f((unsigned short)r[q][1][k]);
                }
            }
        }
    }

    float rd = 1.0f / fmaxf((float)deg, 1.0f);
    short8 o0, o1;
    #pragma unroll
    for (int k = 0; k < 8; ++k) {
        o0[k] = (short)f2bf_raw(acc[k] * rd);
        o1[k] = (short)f2bf_raw(acc[k + 8] * rd);
    }
    short8* op = (short8*)&meanb[(long)n * HD + sub * 16];
    op[0] = o0;
    op[1] = o1;
}

// ---------------- combine: out = act( mean @ Wl.T + b + xin @ Wr.T )   [in-place: out may == xin]
template <bool RELU>
__global__ __launch_bounds__(256) void combine_kernel(
    const unsigned short* __restrict__ meanb,
    const unsigned short* __restrict__ xin,
    const void* __restrict__ Wl,
    const void* __restrict__ bias,
    const void* __restrict__ Wr,
    unsigned short* __restrict__ out,
    const int* __restrict__ flags)
{
    __shared__ short8 lWl8[HD * HD / 8];
    __shared__ short8 lWr8[HD * HD / 8];
    __shared__ short8 lmean8[HD * HD / 8];
    __shared__ short8 lx8[HD * HD / 8];
    __shared__ float lb[HD];
    unsigned short* lWl  = (unsigned short*)lWl8;
    unsigned short* lWr  = (unsigned short*)lWr8;
    unsigned short* lmean = (unsigned short*)lmean8;
    unsigned short* lx   = (unsigned short*)lx8;

    int tid = threadIdx.x;
    int isbf = flags[0];
    if (isbf) {
        const short8* wl8 = (const short8*)Wl;
        const short8* wr8 = (const short8*)Wr;
        for (int i = tid; i < HD * HD / 8; i += 256) { lWl8[i] = wl8[i]; lWr8[i] = wr8[i]; }
    } else {
        const floatx4* wlf = (const floatx4*)Wl;
        const floatx4* wrf = (const floatx4*)Wr;
        for (int i = tid; i < HD * HD / 8; i += 256) {
            floatx4 a = wlf[2 * i], b = wlf[2 * i + 1];
            short8 r;
            r[0]=(short)f2bf_raw(a[0]); r[1]=(short)f2bf_raw(a[1]); r[2]=(short)f2bf_raw(a[2]); r[3]=(short)f2bf_raw(a[3]);
            r[4]=(short)f2bf_raw(b[0]); r[5]=(short)f2bf_raw(b[1]); r[6]=(short)f2bf_raw(b[2]); r[7]=(short)f2bf_raw(b[3]);
            lWl8[i] = r;
            a = wrf[2 * i]; b = wrf[2 * i + 1];
            r[0]=(short)f2bf_raw(a[0]); r[1]=(short)f2bf_raw(a[1]); r[2]=(short)f2bf_raw(a[2]); r[3]=(short)f2bf_raw(a[3]);
            r[4]=(short)f2bf_raw(b[0]); r[5]=(short)f2bf_raw(b[1]); r[6]=(short)f2bf_raw(b[2]); r[7]=(short)f2bf_raw(b[3]);
            lWr8[i] = r;
        }
    }
    if (tid < HD) lb[tid] = ldf(bias, tid, isbf);

    int tile = blockIdx.x;                 // 64 nodes per tile; NT = 64*4375 exactly
    long base = (long)tile * HD * HD;
    const short8* mv = (const short8*)(meanb + base);
    const short8* xv = (const short8*)(xin + base);
    for (int i = tid; i < HD * HD / 8; i += 256) { lmean8[i] = mv[i]; lx8[i] = xv[i]; }
    __syncthreads();      // all reads of this tile's xin complete before any in-place write below

    int w = tid >> 6;
    int lane = tid & 63;
    int mrow = lane & 15;
    int quad = lane >> 4;

    short8 am0 = *(const short8*)&lmean[(w * 16 + mrow) * HD + quad * 8];
    short8 am1 = *(const short8*)&lmean[(w * 16 + mrow) * HD + 32 + quad * 8];
    short8 ax0 = *(const short8*)&lx[(w * 16 + mrow) * HD + quad * 8];
    short8 ax1 = *(const short8*)&lx[(w * 16 + mrow) * HD + 32 + quad * 8];

    floatx4 acc[4];
    #pragma unroll
    for (int ht = 0; ht < 4; ++ht) {
        int h = ht * 16 + mrow;
        short8 bl0 = *(const short8*)&lWl[h * HD + quad * 8];
        short8 bl1 = *(const short8*)&lWl[h * HD + 32 + quad * 8];
        short8 br0 = *(const short8*)&lWr[h * HD + quad * 8];
        short8 br1 = *(const short8*)&lWr[h * HD + 32 + quad * 8];
        floatx4 a = {0.f, 0.f, 0.f, 0.f};
        a = __builtin_amdgcn_mfma_f32_16x16x32_bf16(am0, bl0, a, 0, 0, 0);
        a = __builtin_amdgcn_mfma_f32_16x16x32_bf16(am1, bl1, a, 0, 0, 0);
        a = __builtin_amdgcn_mfma_f32_16x16x32_bf16(ax0, br0, a, 0, 0, 0);
        a = __builtin_amdgcn_mfma_f32_16x16x32_bf16(ax1, br1, a, 0, 0, 0);
        acc[ht] = a;
    }

    #pragma unroll
    for (int ht = 0; ht < 4; ++ht) {
        int h = ht * 16 + mrow;
        float bv = lb[h];
        #pragma unroll
        for (int r = 0; r < 4; ++r) {
            int node = w * 16 + quad * 4 + r;
            float v = acc[ht][r] + bv;
            if (RELU) v = fmaxf(v, 0.0f);
            out[base + node * HD + h] = f2bf_raw(v);
        }
    }
}

// ---------------- final: out[e] = dot(x2[u[e]], x2[NU + m[e]])
// 4 lanes per edge, 16 edges per wave; 16B vector loads; 2-step xor reduce.
__global__ __launch_bounds__(256) void dot_kernel(
    const unsigned short* __restrict__ x2,
    const int* __restrict__ eli,
    void* __restrict__ out,
    int EL,
    const int* __restrict__ flags)
{
    int wid = (blockIdx.x * 256 + threadIdx.x) >> 6;    // global wave id
    long base = (long)wid * 16;                          // first edge of this wave
    if (base >= EL) return;
    int lane = threadIdx.x & 63;
    int isbf = flags[0];
    int is64 = flags[1];

    // lanes 0..15 load u indices, lanes 16..31 load m indices (EL % 16 == 0)
    int idxv = 0;
    if (lane < 16)      idxv = ldidx(eli, base + lane, is64);
    else if (lane < 32) idxv = ldidx(eli, (long)EL + base + (lane - 16), is64);

    int e   = lane >> 2;          // edge slot 0..15
    int seg = lane & 3;           // 16-element segment of the 64-dim row
    int u = __shfl(idxv, e);
    int m = __shfl(idxv, 16 + e);

    const short8* up = (const short8*)(x2 + (long)u * HD + seg * 16);
    const short8* mp = (const short8*)(x2 + (long)(NU + m) * HD + seg * 16);
    short8 a0 = up[0], a1 = up[1];
    short8 b0 = mp[0], b1 = mp[1];

    float p = 0.f;
    #pragma unroll
    for (int j = 0; j < 8; ++j) {
        p += bfu2f((unsigned short)a0[j]) * bfu2f((unsigned short)b0[j]);
        p += bfu2f((unsigned short)a1[j]) * bfu2f((unsigned short)b1[j]);
    }
    p += __shfl_xor(p, 1);
    p += __shfl_xor(p, 2);

    if (seg == 0) {
        long g = base + e;
        if (isbf) ((unsigned short*)out)[g] = f2bf_raw(p);
        else      ((float*)out)[g] = p;
    }
}

extern "C" void kernel_launch(void* const* d_in, const int* in_sizes, int n_in,
                              void* d_out, int out_size, void* d_ws, size_t ws_size,
                              hipStream_t stream)
{
    const void* movie_x   = d_in[0];
    const void* user_emb  = d_in[1];
    const void* movie_emb = d_in[2];
    const void* lin_W     = d_in[3];
    const void* lin_b     = d_in[4];
    const void* W1l       = d_in[5];
    const void* b1        = d_in[6];
    const void* W1r       = d_in[7];
    const void* W2l       = d_in[8];
    const void* b2        = d_in[9];
    const void* W2r       = d_in[10];
    const int* ei  = (const int*)d_in[11];
    const int* eli = (const int*)d_in[12];
    int E  = in_sizes[11] / 2;
    int EL = in_sizes[12] / 2;

    const int NB = (NT + 255) / 256;     // 1094 scan blocks

    char* w = (char*)d_ws;
    unsigned short* xb      = (unsigned short*)w;  w += (size_t)NT * HD * 2;  // 35.84 MB
    unsigned short* meanb   = (unsigned short*)w;  w += (size_t)NT * HD * 2;  // 35.84 MB
    int*            cnt     = (int*)w;             w += (size_t)NT * 4;
    int*            rowptr  = (int*)w;             w += (size_t)NT * 4;
    int*            srclist = (int*)w;             w += (size_t)E * 4;        // 5 MB
    int*            packed  = (int*)w;             w += (size_t)E * 4;        // 5 MB
    int*            bsum    = (int*)w;             w += (size_t)NB * 4;
    int*            bfill   = (int*)w;             w += (size_t)NBUCK * 4;
    int*            flags   = (int*)w;

    const int user_blocks   = (NU * HD / 8) / 256;      // 6250 exactly
    const int movie_blocks  = (NM * 64 + 255) / 256;    // 20000 (wave per movie)
    const int edge_blocks   = (E + 255) / 256;
    const int bucket_blocks = (E + CHUNK - 1) / CHUNK;  // 611
    const int gather_blocks = ((NT / 16) * 64 + 255) / 256;  // 4375 (16 nodes/wave)
    const int tile_blocks   = NT / 64;                  // 4375
    const int dot_blocks    = ((EL + 15) / 16 + 3) / 4; // 7813

    probe_kernel<<<1, 64, 0, stream>>>(user_emb, ei, flags);

    prep_user<<<user_blocks, 256, 0, stream>>>(user_emb, xb, flags);
    prep_movie<<<movie_blocks, 256, 0, stream>>>(movie_x, movie_emb, lin_W, lin_b, xb, flags);

    // CSR build (once; reused by both layers)
    hipMemsetAsync(cnt, 0, (size_t)NT * 4, stream);
    hipMemsetAsync(bfill, 0, (size_t)NBUCK * 4, stream);
    hist_kernel<<<edge_blocks, 256, 0, stream>>>(ei, E, cnt, flags);
    scan1_kernel<<<NB, 256, 0, stream>>>(cnt, bsum);
    scan2_kernel<<<1, 256, 0, stream>>>(bsum, NB);
    scan3_kernel<<<NB, 256, 0, stream>>>(cnt, bsum, rowptr);
    bucket_kernel<<<bucket_blocks, 256, 0, stream>>>(ei, E, rowptr, bfill, packed, flags);
    finefill_kernel<<<NBUCK, 256, 0, stream>>>(rowptr, packed, srclist, E);

    // layer 1
    gather_mean<<<gather_blocks, 256, 0, stream>>>(xb, rowptr, cnt, srclist, meanb);
    combine_kernel<true><<<tile_blocks, 256, 0, stream>>>(meanb, xb, W1l, b1, W1r, xb, flags);

    // layer 2
    gather_mean<<<gather_blocks, 256, 0, stream>>>(xb, rowptr, cnt, srclist, meanb);
    combine_kernel<false><<<tile_blocks, 256, 0, stream>>>(meanb, xb, W2l, b2, W2r, xb, flags);

    // final edge dot products
    dot_kernel<<<dot_blocks, 256, 0, stream>>>(xb, eli, d_out, EL, flags);
}